// Round 7
// baseline (741.743 us; speedup 1.0000x reference)
//
#include <hip/hip_runtime.h>
#include <hip/hip_bf16.h>

typedef __bf16 bf16_t;
typedef __bf16 bf16x8 __attribute__((ext_vector_type(8)));
typedef __bf16 bf16x4 __attribute__((ext_vector_type(4)));
typedef float f32x4 __attribute__((ext_vector_type(4)));
typedef unsigned int u32;

#define NUM_USER 200000
#define NUM_ITEM 200000
#define DIM_E 64
#define DIM_FEAT 128
#define HID 256
#define BATCH 16384
#define GG 17
#define NN (BATCH * GG)   // 278528
#define NREP 139264       // int(NN * 0.5)
#define W1LP 136          // W1 LDS pitch (bf16)
#define W2LP 264          // W2 LDS pitch (bf16)
#define NWAVES 4096       // 256 blocks x 16 waves
#define NSP 6250          // strip-pairs: 6250 * 32 == 200000
#define LGRID 5462        // ceil(16384 / 3) batch-rows, 3 per block

// ---------------------------------------------------------------------------
// K1: weights -> bf16, N-major. W1 rows PERMUTED so that phase-1 C-fragments
//     concatenate directly into phase-2 B-fragments (no shuffle transform):
//     LDS row p holds W1 column c(p) = (p&~31) | ((p>>2)&3)*8 | ((p>>4)&1)*4 | (p&3)
// ---------------------------------------------------------------------------
__global__ __launch_bounds__(256) void prep3_kernel(
    const float* __restrict__ W1, const float* __restrict__ W2,
    const int* __restrict__ rand_index,
    bf16_t* __restrict__ W1t, bf16_t* __restrict__ W2t,
    unsigned char* __restrict__ mask)
{
    const int t = blockIdx.x * 256 + threadIdx.x;
    if (t < HID * DIM_FEAT) {            // t = p*128 + k
        const int p = t >> 7, k = t & 127;
        const int c = (p & ~31) | (((p >> 2) & 3) << 3) | (((p >> 4) & 1) << 2) | (p & 3);
        W1t[t] = (bf16_t)W1[k * HID + c];
    }
    if (t < DIM_E * HID) {               // W2t[n][k], n<64, k<256
        const int n = t >> 8, k = t & 255;
        W2t[t] = (bf16_t)W2[k * DIM_E + n];
    }
    if (t < NREP) mask[rand_index[t]] = 1;
}

// ---------------------------------------------------------------------------
// K2: encoder v7. 1024-thread block (16 waves/CU), weights LDS-resident.
//   Permuted W1 => phase1 D-regs concat straight into phase2 B-frag:
//   inner loop = 12 ds_read_b128 + 24 MFMA + cvt/pack. No shuffles, 1 barrier.
// ---------------------------------------------------------------------------
__global__ __launch_bounds__(1024, 4) void encoder7_kernel(
    const float* __restrict__ vfeat,
    const bf16_t* __restrict__ W1t, const float* __restrict__ b1v,
    const bf16_t* __restrict__ W2t, const float* __restrict__ b2v,
    bf16_t* __restrict__ featB)
{
    const int tid  = threadIdx.x;
    const int wave = tid >> 6;
    const int lane = tid & 63;
    const int r    = lane & 15;          // item-row within strip
    const int Q    = lane >> 4;          // quad

    __shared__ bf16_t w1s[256 * W1LP];   // 69632 B
    __shared__ bf16_t w2s[64 * W2LP];    // 33792 B
    __shared__ float  b1s[HID];
    __shared__ float  b2s[DIM_E];

    // ---- stage weights once ----
#pragma unroll
    for (int c = tid; c < 4096; c += 1024) {       // W1t: 4096 uint4
        const int n = c >> 4, ks = c & 15;
        *reinterpret_cast<uint4*>(&w1s[n * W1LP + ks * 8]) =
            reinterpret_cast<const uint4*>(W1t)[c];
    }
#pragma unroll
    for (int c = tid; c < 2048; c += 1024) {       // W2t: 2048 uint4
        const int n = c >> 5, ks = c & 31;
        *reinterpret_cast<uint4*>(&w2s[n * W2LP + ks * 8]) =
            reinterpret_cast<const uint4*>(W2t)[c];
    }
    if (tid < HID) b1s[tid] = b1v[tid];
    if (tid < DIM_E) b2s[tid] = b2v[tid];
    __syncthreads();                                // the only barrier

    for (int sp = blockIdx.x * 16 + wave; sp < NSP; sp += NWAVES) {
        const size_t row0 = (size_t)sp * 32;

        // ---- A-phase: 2 strips of 16 v_feat rows, fused l2norm ----
        bf16x8 af[2][4];
#pragma unroll
        for (int s = 0; s < 2; ++s) {
            const float* rp = vfeat + (row0 + s * 16 + r) * DIM_FEAT + Q * 8;
            float4 v0[4], v1[4];
#pragma unroll
            for (int ks = 0; ks < 4; ++ks) {
                v0[ks] = *reinterpret_cast<const float4*>(rp + ks * 32);
                v1[ks] = *reinterpret_cast<const float4*>(rp + ks * 32 + 4);
            }
            float ss = 0.f;
#pragma unroll
            for (int ks = 0; ks < 4; ++ks) {
                ss += v0[ks].x * v0[ks].x + v0[ks].y * v0[ks].y
                    + v0[ks].z * v0[ks].z + v0[ks].w * v0[ks].w;
                ss += v1[ks].x * v1[ks].x + v1[ks].y * v1[ks].y
                    + v1[ks].z * v1[ks].z + v1[ks].w * v1[ks].w;
            }
            ss += __shfl_xor(ss, 16, 64);
            ss += __shfl_xor(ss, 32, 64);
            const float inv = 1.0f / fmaxf(sqrtf(ss), 1e-12f);
#pragma unroll
            for (int ks = 0; ks < 4; ++ks) {
                bf16x8 v;
                v[0] = (bf16_t)(v0[ks].x * inv); v[1] = (bf16_t)(v0[ks].y * inv);
                v[2] = (bf16_t)(v0[ks].z * inv); v[3] = (bf16_t)(v0[ks].w * inv);
                v[4] = (bf16_t)(v1[ks].x * inv); v[5] = (bf16_t)(v1[ks].y * inv);
                v[6] = (bf16_t)(v1[ks].z * inv); v[7] = (bf16_t)(v1[ks].w * inv);
                af[s][ks] = v;
            }
        }

        f32x4 acc2[2][4];
#pragma unroll
        for (int s = 0; s < 2; ++s)
#pragma unroll
            for (int n2 = 0; n2 < 4; ++n2) acc2[s][n2] = (f32x4){0.f, 0.f, 0.f, 0.f};

#pragma unroll
        for (int t = 0; t < 8; ++t) {
            // ---- phase 1: two h-tiles; lane ends holding cols Q*8..Q*8+7 ----
            bf16x4 hv[2][2];   // [strip][h]
#pragma unroll
            for (int h = 0; h < 2; ++h) {
                const int nt = t * 2 + h;
                const bf16_t* bp = &w1s[(nt * 16 + r) * W1LP + Q * 8];
                bf16x8 w1f[4];
#pragma unroll
                for (int ks = 0; ks < 4; ++ks)
                    w1f[ks] = *reinterpret_cast<const bf16x8*>(bp + ks * 32);
                // permuted bias: D-row Q*4+i of tile nt is h-col t*32+Q*8+h*4+i
                const float4 bias1 = *reinterpret_cast<const float4*>(
                    &b1s[t * 32 + Q * 8 + h * 4]);
#pragma unroll
                for (int s = 0; s < 2; ++s) {
                    f32x4 a1 = (f32x4){0.f, 0.f, 0.f, 0.f};
#pragma unroll
                    for (int ks = 0; ks < 4; ++ks)
                        a1 = __builtin_amdgcn_mfma_f32_16x16x32_bf16(w1f[ks], af[s][ks], a1, 0, 0, 0);
                    bf16x4 hv4;
#pragma unroll
                    for (int i = 0; i < 4; ++i) {
                        float x = a1[i] + ((const float*)&bias1)[i];
                        x = x >= 0.f ? x : 0.01f * x;
                        hv4[i] = (bf16_t)x;
                    }
                    hv[s][h] = hv4;
                }
            }
            // ---- W2 fragments for k in [32t, 32t+32) from LDS ----
            bf16x8 w2f[4];
#pragma unroll
            for (int n2 = 0; n2 < 4; ++n2)
                w2f[n2] = *reinterpret_cast<const bf16x8*>(
                    &w2s[(n2 * 16 + r) * W2LP + t * 32 + Q * 8]);
            // ---- phase 2: B-frag = concat of the two C-frags ----
#pragma unroll
            for (int s = 0; s < 2; ++s) {
                bf16x8 hf;
#pragma unroll
                for (int j = 0; j < 4; ++j) { hf[j] = hv[s][0][j]; hf[j + 4] = hv[s][1][j]; }
#pragma unroll
                for (int n2 = 0; n2 < 4; ++n2)
                    acc2[s][n2] = __builtin_amdgcn_mfma_f32_16x16x32_bf16(w2f[n2], hf, acc2[s][n2], 0, 0, 0);
            }
        }

        // ---- epilogue: bias + packed bf16 stores ----
#pragma unroll
        for (int n2 = 0; n2 < 4; ++n2) {
            const float4 bias2 = *reinterpret_cast<const float4*>(&b2s[n2 * 16 + Q * 4]);
#pragma unroll
            for (int s = 0; s < 2; ++s) {
                bf16x4 o;
                o[0] = (bf16_t)(acc2[s][n2][0] + bias2.x);
                o[1] = (bf16_t)(acc2[s][n2][1] + bias2.y);
                o[2] = (bf16_t)(acc2[s][n2][2] + bias2.z);
                o[3] = (bf16_t)(acc2[s][n2][3] + bias2.w);
                *reinterpret_cast<bf16x4*>(
                    featB + (row0 + s * 16 + r) * DIM_E + n2 * 16 + Q * 4) = o;
            }
        }
    }
}

// ---------------------------------------------------------------------------
// K3: fused loss. Block = 3 batch-rows (51 elements x 4 lanes = 204 active).
//   4-lane dot products -> LDS -> per-row softmax loss -> device atomics;
//   last-ticket block writes d_out (no separate reduce kernel, no d_out memset)
// ---------------------------------------------------------------------------
__global__ __launch_bounds__(256) void loss_fused_kernel(
    const bf16_t* __restrict__ featB, const float* __restrict__ id_emb,
    const int* __restrict__ user_t, const int* __restrict__ item_t,
    const unsigned char* __restrict__ mask,
    float* __restrict__ accum, u32* __restrict__ counter,
    float* __restrict__ out)
{
    __shared__ float s1l[52], s2l[52], rowv[3];
    const int kq   = threadIdx.x & 3;            // dims [kq*16, kq*16+16)
    const int eidx = threadIdx.x >> 2;           // 0..63
    const int bl   = eidx / 17;
    const int g    = eidx - bl * 17;
    const int b    = blockIdx.x * 3 + bl;

    if (eidx < 51 && b < BATCH) {
        const int n  = b * GG + g;
        const int u  = user_t[n];
        const int it = item_t[n];
        const int pos = item_t[b * GG];
        const int fidx = min(max(it - NUM_USER, 0), NUM_ITEM - 1);
        const bool rep = mask[n] != 0;

        const bf16x8* fp = reinterpret_cast<const bf16x8*>(featB + (size_t)fidx * DIM_E + kq * 16);
        const float4* pp = reinterpret_cast<const float4*>(id_emb + (size_t)pos * DIM_E) + kq * 4;
        const float4* up = reinterpret_cast<const float4*>(id_emb + (size_t)u   * DIM_E) + kq * 4;
        const float4* ip = reinterpret_cast<const float4*>(id_emb + (size_t)it  * DIM_E) + kq * 4;

        const bf16x8 f8a = fp[0];
        const bf16x8 f8b = fp[1];

        float x = 0.f, y = 0.f, z = 0.f, w = 0.f;
#pragma unroll
        for (int j = 0; j < 4; ++j) {
            const float4 p  = pp[j];
            const float4 uu = up[j];
            const float4 iv = ip[j];
            const bf16x8 fb = (j < 2) ? f8a : f8b;
            const float f0 = (float)fb[(j & 1) * 4 + 0];
            const float f1 = (float)fb[(j & 1) * 4 + 1];
            const float f2 = (float)fb[(j & 1) * 4 + 2];
            const float f3 = (float)fb[(j & 1) * 4 + 3];
            const float a0 = rep ? f0 : iv.x;
            const float a1 = rep ? f1 : iv.y;
            const float a2 = rep ? f2 : iv.z;
            const float a3 = rep ? f3 : iv.w;
            x += f0 * f0 + f1 * f1 + f2 * f2 + f3 * f3;
            y += p.x * p.x + p.y * p.y + p.z * p.z + p.w * p.w;
            z += p.x * f0 + p.y * f1 + p.z * f2 + p.w * f3;
            w += uu.x * a0 + uu.y * a1 + uu.z * a2 + uu.w * a3;
        }
#pragma unroll
        for (int off = 1; off <= 2; off <<= 1) {
            x += __shfl_xor(x, off, 64);
            y += __shfl_xor(y, off, 64);
            z += __shfl_xor(z, off, 64);
            w += __shfl_xor(w, off, 64);
        }
        if (kq == 0) {
            const float dot1 = z / (fmaxf(sqrtf(x), 1e-12f) * fmaxf(sqrtf(y), 1e-12f));
            s1l[eidx] = __expf(dot1 * 5.0f);   // 1/TEMP = 5
            s2l[eidx] = __expf(w * 5.0f);
        }
    }
    __syncthreads();

    if (threadIdx.x < 3) {
        const int bb = blockIdx.x * 3 + threadIdx.x;
        float v = 0.f;
        if (bb < BATCH) {
            const int base = threadIdx.x * 17;
            float tot1 = 0.f, tot2 = 0.f;
#pragma unroll
            for (int gg = 0; gg < GG; ++gg) { tot1 += s1l[base + gg]; tot2 += s2l[base + gg]; }
            const float l1 = -logf(s1l[base] / (tot1 + 1e-8f) + 1e-8f);
            const float l2 = -logf(s2l[base] / (tot2 + 1e-8f) + 1e-8f);
            v = (0.5f * l1 + 0.5f * l2) * (1.0f / BATCH);
        }
        rowv[threadIdx.x] = v;
    }
    __syncthreads();

    if (threadIdx.x == 0) {
        atomicAdd(accum, rowv[0] + rowv[1] + rowv[2]);
        __threadfence();
        const u32 ticket = atomicAdd(counter, 1u);
        if (ticket == (u32)(LGRID - 1)) {
            out[0] = atomicAdd(accum, 0.0f);   // returns completed total
        }
    }
}

// ---------------------------------------------------------------------------
extern "C" void kernel_launch(void* const* d_in, const int* in_sizes, int n_in,
                              void* d_out, int out_size, void* d_ws, size_t ws_size,
                              hipStream_t stream)
{
    (void)in_sizes; (void)n_in; (void)out_size; (void)ws_size;
    const float* v_feat    = (const float*)d_in[0];
    const float* id_emb    = (const float*)d_in[1];
    const float* W1        = (const float*)d_in[2];
    const float* b1        = (const float*)d_in[3];
    const float* W2        = (const float*)d_in[4];
    const float* b2        = (const float*)d_in[5];
    const int*   user_t    = (const int*)d_in[6];
    const int*   item_t    = (const int*)d_in[7];
    const int*   rand_idx  = (const int*)d_in[8];

    char* ws = (char*)d_ws;
    bf16_t*        W1t      = (bf16_t*)(ws + 0);             // 65536
    bf16_t*        W2t      = (bf16_t*)(ws + 65536);         // 32768
    unsigned char* mask     = (unsigned char*)(ws + 98304);  // 278528
    u32*           counter  = (u32*)(ws + 376832);           // 4
    float*         accum    = (float*)(ws + 376836);         // 4
    bf16_t*        featB    = (bf16_t*)(ws + 376896);        // 25600000

    hipMemsetAsync(ws + 98304, 0, NN + 8, stream);           // mask + counter + accum
    prep3_kernel<<<544, 256, 0, stream>>>(W1, W2, rand_idx, W1t, W2t, mask);
    encoder7_kernel<<<256, 1024, 0, stream>>>(v_feat, W1t, b1, W2t, b2, featB);
    loss_fused_kernel<<<LGRID, 256, 0, stream>>>(featB, id_emb, user_t, item_t, mask,
                                                 accum, counter, (float*)d_out);
}

// Round 8
// 613.042 us; speedup vs baseline: 1.2099x; 1.2099x over previous
//
#include <hip/hip_runtime.h>
#include <hip/hip_bf16.h>

typedef __bf16 bf16_t;
typedef __bf16 bf16x8 __attribute__((ext_vector_type(8)));
typedef __bf16 bf16x4 __attribute__((ext_vector_type(4)));
typedef float f32x4 __attribute__((ext_vector_type(4)));
typedef unsigned int u32;

#define NUM_USER 200000
#define NUM_ITEM 200000
#define DIM_E 64
#define DIM_FEAT 128
#define HID 256
#define BATCH 16384
#define GG 17
#define NN (BATCH * GG)   // 278528
#define NREP 139264       // int(NN * 0.5)
#define W1LP 136          // W1 LDS pitch (bf16)
#define W2LP 264          // W2 LDS pitch (bf16)
#define NWAVES 4096       // 256 blocks x 16 waves
#define NSP 6250          // strip-pairs: 6250 * 32 == 200000
#define LROWS 7           // batch-rows per loss block (512 thr = 128 slots, 119 used)
#define LGRID 2341        // ceil(16384 / 7)

// ---------------------------------------------------------------------------
// K1: weights -> bf16, N-major. W1 rows PERMUTED so that phase-1 C-fragments
//     concatenate directly into phase-2 B-fragments (no shuffle transform):
//     LDS row p holds W1 column c(p) = (p&~31) | ((p>>2)&3)*8 | ((p>>4)&1)*4 | (p&3)
// ---------------------------------------------------------------------------
__global__ __launch_bounds__(256) void prep3_kernel(
    const float* __restrict__ W1, const float* __restrict__ W2,
    const int* __restrict__ rand_index,
    bf16_t* __restrict__ W1t, bf16_t* __restrict__ W2t,
    unsigned char* __restrict__ mask)
{
    const int t = blockIdx.x * 256 + threadIdx.x;
    if (t < HID * DIM_FEAT) {            // t = p*128 + k
        const int p = t >> 7, k = t & 127;
        const int c = (p & ~31) | (((p >> 2) & 3) << 3) | (((p >> 4) & 1) << 2) | (p & 3);
        W1t[t] = (bf16_t)W1[k * HID + c];
    }
    if (t < DIM_E * HID) {               // W2t[n][k], n<64, k<256
        const int n = t >> 8, k = t & 255;
        W2t[t] = (bf16_t)W2[k * DIM_E + n];
    }
    if (t < NREP) mask[rand_index[t]] = 1;
}

// ---------------------------------------------------------------------------
// K2: encoder v8 = v7 body, FIXED launch bounds.
//   __launch_bounds__(1024, 1): 1 block/CU (LDS-bound anyway), VGPR cap 128
//   -> no spills (v7's (1024,4) capped at 64 VGPR and spilled ~880 MB/dispatch).
//   Inner loop: 12 ds_read_b128 + 24 MFMA + cvt/pack. No shuffles, 1 barrier.
// ---------------------------------------------------------------------------
__global__ __launch_bounds__(1024, 1) void encoder8_kernel(
    const float* __restrict__ vfeat,
    const bf16_t* __restrict__ W1t, const float* __restrict__ b1v,
    const bf16_t* __restrict__ W2t, const float* __restrict__ b2v,
    bf16_t* __restrict__ featB)
{
    const int tid  = threadIdx.x;
    const int wave = tid >> 6;
    const int lane = tid & 63;
    const int r    = lane & 15;          // item-row within strip
    const int Q    = lane >> 4;          // quad

    __shared__ bf16_t w1s[256 * W1LP];   // 69632 B
    __shared__ bf16_t w2s[64 * W2LP];    // 33792 B
    __shared__ float  b1s[HID];
    __shared__ float  b2s[DIM_E];

    // ---- stage weights once ----
#pragma unroll
    for (int c = tid; c < 4096; c += 1024) {       // W1t: 4096 uint4
        const int n = c >> 4, ks = c & 15;
        *reinterpret_cast<uint4*>(&w1s[n * W1LP + ks * 8]) =
            reinterpret_cast<const uint4*>(W1t)[c];
    }
#pragma unroll
    for (int c = tid; c < 2048; c += 1024) {       // W2t: 2048 uint4
        const int n = c >> 5, ks = c & 31;
        *reinterpret_cast<uint4*>(&w2s[n * W2LP + ks * 8]) =
            reinterpret_cast<const uint4*>(W2t)[c];
    }
    if (tid < HID) b1s[tid] = b1v[tid];
    if (tid < DIM_E) b2s[tid] = b2v[tid];
    __syncthreads();                                // the only barrier

    for (int sp = blockIdx.x * 16 + wave; sp < NSP; sp += NWAVES) {
        const size_t row0 = (size_t)sp * 32;

        // ---- A-phase: 2 strips of 16 v_feat rows, fused l2norm ----
        bf16x8 af[2][4];
#pragma unroll
        for (int s = 0; s < 2; ++s) {
            const float* rp = vfeat + (row0 + s * 16 + r) * DIM_FEAT + Q * 8;
            float4 v0[4], v1[4];
#pragma unroll
            for (int ks = 0; ks < 4; ++ks) {
                v0[ks] = *reinterpret_cast<const float4*>(rp + ks * 32);
                v1[ks] = *reinterpret_cast<const float4*>(rp + ks * 32 + 4);
            }
            float ss = 0.f;
#pragma unroll
            for (int ks = 0; ks < 4; ++ks) {
                ss += v0[ks].x * v0[ks].x + v0[ks].y * v0[ks].y
                    + v0[ks].z * v0[ks].z + v0[ks].w * v0[ks].w;
                ss += v1[ks].x * v1[ks].x + v1[ks].y * v1[ks].y
                    + v1[ks].z * v1[ks].z + v1[ks].w * v1[ks].w;
            }
            ss += __shfl_xor(ss, 16, 64);
            ss += __shfl_xor(ss, 32, 64);
            const float inv = 1.0f / fmaxf(sqrtf(ss), 1e-12f);
#pragma unroll
            for (int ks = 0; ks < 4; ++ks) {
                bf16x8 v;
                v[0] = (bf16_t)(v0[ks].x * inv); v[1] = (bf16_t)(v0[ks].y * inv);
                v[2] = (bf16_t)(v0[ks].z * inv); v[3] = (bf16_t)(v0[ks].w * inv);
                v[4] = (bf16_t)(v1[ks].x * inv); v[5] = (bf16_t)(v1[ks].y * inv);
                v[6] = (bf16_t)(v1[ks].z * inv); v[7] = (bf16_t)(v1[ks].w * inv);
                af[s][ks] = v;
            }
        }

        f32x4 acc2[2][4];
#pragma unroll
        for (int s = 0; s < 2; ++s)
#pragma unroll
            for (int n2 = 0; n2 < 4; ++n2) acc2[s][n2] = (f32x4){0.f, 0.f, 0.f, 0.f};

#pragma unroll
        for (int t = 0; t < 8; ++t) {
            // ---- phase 1: two h-tiles; lane ends holding cols Q*8..Q*8+7 ----
            bf16x4 hv[2][2];   // [strip][h]
#pragma unroll
            for (int h = 0; h < 2; ++h) {
                const int nt = t * 2 + h;
                const bf16_t* bp = &w1s[(nt * 16 + r) * W1LP + Q * 8];
                bf16x8 w1f[4];
#pragma unroll
                for (int ks = 0; ks < 4; ++ks)
                    w1f[ks] = *reinterpret_cast<const bf16x8*>(bp + ks * 32);
                // permuted bias: D-row Q*4+i of tile nt is h-col t*32+Q*8+h*4+i
                const float4 bias1 = *reinterpret_cast<const float4*>(
                    &b1s[t * 32 + Q * 8 + h * 4]);
#pragma unroll
                for (int s = 0; s < 2; ++s) {
                    f32x4 a1 = (f32x4){0.f, 0.f, 0.f, 0.f};
#pragma unroll
                    for (int ks = 0; ks < 4; ++ks)
                        a1 = __builtin_amdgcn_mfma_f32_16x16x32_bf16(w1f[ks], af[s][ks], a1, 0, 0, 0);
                    bf16x4 hv4;
#pragma unroll
                    for (int i = 0; i < 4; ++i) {
                        float x = a1[i] + ((const float*)&bias1)[i];
                        x = x >= 0.f ? x : 0.01f * x;
                        hv4[i] = (bf16_t)x;
                    }
                    hv[s][h] = hv4;
                }
            }
            // ---- W2 fragments for k in [32t, 32t+32) from LDS ----
            bf16x8 w2f[4];
#pragma unroll
            for (int n2 = 0; n2 < 4; ++n2)
                w2f[n2] = *reinterpret_cast<const bf16x8*>(
                    &w2s[(n2 * 16 + r) * W2LP + t * 32 + Q * 8]);
            // ---- phase 2: B-frag = concat of the two C-frags ----
#pragma unroll
            for (int s = 0; s < 2; ++s) {
                bf16x8 hf;
#pragma unroll
                for (int j = 0; j < 4; ++j) { hf[j] = hv[s][0][j]; hf[j + 4] = hv[s][1][j]; }
#pragma unroll
                for (int n2 = 0; n2 < 4; ++n2)
                    acc2[s][n2] = __builtin_amdgcn_mfma_f32_16x16x32_bf16(w2f[n2], hf, acc2[s][n2], 0, 0, 0);
            }
        }

        // ---- epilogue: bias + packed bf16 stores ----
#pragma unroll
        for (int n2 = 0; n2 < 4; ++n2) {
            const float4 bias2 = *reinterpret_cast<const float4*>(&b2s[n2 * 16 + Q * 4]);
#pragma unroll
            for (int s = 0; s < 2; ++s) {
                bf16x4 o;
                o[0] = (bf16_t)(acc2[s][n2][0] + bias2.x);
                o[1] = (bf16_t)(acc2[s][n2][1] + bias2.y);
                o[2] = (bf16_t)(acc2[s][n2][2] + bias2.z);
                o[3] = (bf16_t)(acc2[s][n2][3] + bias2.w);
                *reinterpret_cast<bf16x4*>(
                    featB + (row0 + s * 16 + r) * DIM_E + n2 * 16 + Q * 4) = o;
            }
        }
    }
}

// ---------------------------------------------------------------------------
// K3: fused loss. 512-thread block = 7 batch-rows (119 of 128 element slots).
//   4-lane dot products -> LDS -> per-row softmax loss -> device atomics;
//   last-ticket block writes d_out.
// ---------------------------------------------------------------------------
__global__ __launch_bounds__(512) void loss_fused_kernel(
    const bf16_t* __restrict__ featB, const float* __restrict__ id_emb,
    const int* __restrict__ user_t, const int* __restrict__ item_t,
    const unsigned char* __restrict__ mask,
    float* __restrict__ accum, u32* __restrict__ counter,
    float* __restrict__ out)
{
    __shared__ float s1l[120], s2l[120], rowv[LROWS];
    const int kq   = threadIdx.x & 3;            // dims [kq*16, kq*16+16)
    const int eidx = threadIdx.x >> 2;           // 0..127
    const int bl   = eidx / 17;
    const int g    = eidx - bl * 17;
    const int b    = blockIdx.x * LROWS + bl;

    if (bl < LROWS && b < BATCH) {
        const int n  = b * GG + g;
        const int u  = user_t[n];
        const int it = item_t[n];
        const int pos = item_t[b * GG];
        const int fidx = min(max(it - NUM_USER, 0), NUM_ITEM - 1);
        const bool rep = mask[n] != 0;

        const bf16x8* fp = reinterpret_cast<const bf16x8*>(featB + (size_t)fidx * DIM_E + kq * 16);
        const float4* pp = reinterpret_cast<const float4*>(id_emb + (size_t)pos * DIM_E) + kq * 4;
        const float4* up = reinterpret_cast<const float4*>(id_emb + (size_t)u   * DIM_E) + kq * 4;
        const float4* ip = reinterpret_cast<const float4*>(id_emb + (size_t)it  * DIM_E) + kq * 4;

        const bf16x8 f8a = fp[0];
        const bf16x8 f8b = fp[1];

        float x = 0.f, y = 0.f, z = 0.f, w = 0.f;
#pragma unroll
        for (int j = 0; j < 4; ++j) {
            const float4 p  = pp[j];
            const float4 uu = up[j];
            const float4 iv = ip[j];
            const bf16x8 fb = (j < 2) ? f8a : f8b;
            const float f0 = (float)fb[(j & 1) * 4 + 0];
            const float f1 = (float)fb[(j & 1) * 4 + 1];
            const float f2 = (float)fb[(j & 1) * 4 + 2];
            const float f3 = (float)fb[(j & 1) * 4 + 3];
            const float a0 = rep ? f0 : iv.x;
            const float a1 = rep ? f1 : iv.y;
            const float a2 = rep ? f2 : iv.z;
            const float a3 = rep ? f3 : iv.w;
            x += f0 * f0 + f1 * f1 + f2 * f2 + f3 * f3;
            y += p.x * p.x + p.y * p.y + p.z * p.z + p.w * p.w;
            z += p.x * f0 + p.y * f1 + p.z * f2 + p.w * f3;
            w += uu.x * a0 + uu.y * a1 + uu.z * a2 + uu.w * a3;
        }
#pragma unroll
        for (int off = 1; off <= 2; off <<= 1) {
            x += __shfl_xor(x, off, 64);
            y += __shfl_xor(y, off, 64);
            z += __shfl_xor(z, off, 64);
            w += __shfl_xor(w, off, 64);
        }
        if (kq == 0) {
            const float dot1 = z / (fmaxf(sqrtf(x), 1e-12f) * fmaxf(sqrtf(y), 1e-12f));
            s1l[eidx] = __expf(dot1 * 5.0f);   // 1/TEMP = 5
            s2l[eidx] = __expf(w * 5.0f);
        }
    }
    __syncthreads();

    if (threadIdx.x < LROWS) {
        const int bb = blockIdx.x * LROWS + threadIdx.x;
        float v = 0.f;
        if (bb < BATCH) {
            const int base = threadIdx.x * 17;
            float tot1 = 0.f, tot2 = 0.f;
#pragma unroll
            for (int gg = 0; gg < GG; ++gg) { tot1 += s1l[base + gg]; tot2 += s2l[base + gg]; }
            const float l1 = -logf(s1l[base] / (tot1 + 1e-8f) + 1e-8f);
            const float l2 = -logf(s2l[base] / (tot2 + 1e-8f) + 1e-8f);
            v = (0.5f * l1 + 0.5f * l2) * (1.0f / BATCH);
        }
        rowv[threadIdx.x] = v;
    }
    __syncthreads();

    if (threadIdx.x == 0) {
        float bs = 0.f;
#pragma unroll
        for (int i = 0; i < LROWS; ++i) bs += rowv[i];
        atomicAdd(accum, bs);
        __threadfence();
        const u32 ticket = atomicAdd(counter, 1u);
        if (ticket == (u32)(LGRID - 1)) {
            out[0] = atomicAdd(accum, 0.0f);   // returns completed total
        }
    }
}

// ---------------------------------------------------------------------------
extern "C" void kernel_launch(void* const* d_in, const int* in_sizes, int n_in,
                              void* d_out, int out_size, void* d_ws, size_t ws_size,
                              hipStream_t stream)
{
    (void)in_sizes; (void)n_in; (void)out_size; (void)ws_size;
    const float* v_feat    = (const float*)d_in[0];
    const float* id_emb    = (const float*)d_in[1];
    const float* W1        = (const float*)d_in[2];
    const float* b1        = (const float*)d_in[3];
    const float* W2        = (const float*)d_in[4];
    const float* b2        = (const float*)d_in[5];
    const int*   user_t    = (const int*)d_in[6];
    const int*   item_t    = (const int*)d_in[7];
    const int*   rand_idx  = (const int*)d_in[8];

    char* ws = (char*)d_ws;
    bf16_t*        W1t      = (bf16_t*)(ws + 0);             // 65536
    bf16_t*        W2t      = (bf16_t*)(ws + 65536);         // 32768
    unsigned char* mask     = (unsigned char*)(ws + 98304);  // 278528
    u32*           counter  = (u32*)(ws + 376832);           // 4
    float*         accum    = (float*)(ws + 376836);         // 4
    bf16_t*        featB    = (bf16_t*)(ws + 376896);        // 25600000

    hipMemsetAsync(ws + 98304, 0, NN + 8, stream);           // mask + counter + accum
    prep3_kernel<<<544, 256, 0, stream>>>(W1, W2, rand_idx, W1t, W2t, mask);
    encoder8_kernel<<<256, 1024, 0, stream>>>(v_feat, W1t, b1, W2t, b2, featB);
    loss_fused_kernel<<<LGRID, 512, 0, stream>>>(featB, id_emb, user_t, item_t, mask,
                                                 accum, counter, (float*)d_out);
}